// Round 3
// baseline (269.469 us; speedup 1.0000x reference)
//
#include <hip/hip_runtime.h>
#include <math.h>

// B=2048, N=8192, fp32. Three-phase pipeline: histogram -> per-row Newton -> epilogue.
#define N_COLS  8192
#define BLOCK   256
#define VPT     (N_COLS / BLOCK)   // 32 elems/thread
#define F4PT    (VPT / 4)          // 8 float4 groups/thread
#define NBINS   2048               // 16 octaves x 128 bins (log-domain)
#define BIN_OFF 14720              // (127-12)<<7 : bin 0 starts at r = 2^-12
#define BPL     (NBINS / 64)       // 32 bins per lane in the Newton wave

// d_out[0] must be zeroed every call (harness re-poisons to 0xAA).
__global__ void zero_out_kernel(float* out) {
    if (threadIdx.x == 0 && blockIdx.x == 0) out[0] = 0.0f;
}

// ---- K1: per-row log-domain histogram + exact rmax (pure streaming pass) ----
// Log bins need NO rmax -> single phase, one barrier pair total.
__global__ __launch_bounds__(BLOCK) void k1_hist(
        const float* __restrict__ y_pred, const float* __restrict__ y_true,
        unsigned* __restrict__ hist, float* __restrict__ rmaxv) {
    __shared__ unsigned s_hist[NBINS];
    __shared__ float s_wmax[4];
    const int row = blockIdx.x, tid = threadIdx.x;
    const int lane = tid & 63, wid = tid >> 6;
    const size_t base = (size_t)row * N_COLS;
    const float4* yp4 = (const float4*)(y_pred + base);
    const float4* yt4 = (const float4*)(y_true + base);

    #pragma unroll
    for (int i = 0; i < NBINS / BLOCK; ++i) s_hist[tid + i * BLOCK] = 0u;
    __syncthreads();

    float rmax = 0.0f;
    #pragma unroll
    for (int j = 0; j < F4PT; ++j) {
        const int g = j * BLOCK + tid;     // coalesced float4
        float4 a = yt4[g], b = yp4[g];
        float rv[4] = {fabsf(a.x - b.x), fabsf(a.y - b.y),
                       fabsf(a.z - b.z), fabsf(a.w - b.w)};
        #pragma unroll
        for (int c = 0; c < 4; ++c) {
            rmax = fmaxf(rmax, rv[c]);
            // bin = exponent + top-7 mantissa bits (window [2^-12, 2^4))
            int idx = (int)(__float_as_uint(rv[c]) >> 16) - BIN_OFF;
            idx = min(max(idx, 0), NBINS - 1);
            atomicAdd(&s_hist[idx], 1u);
        }
    }
    #pragma unroll
    for (int m = 32; m >= 1; m >>= 1) rmax = fmaxf(rmax, __shfl_xor(rmax, m, 64));
    if (lane == 0) s_wmax[wid] = rmax;
    __syncthreads();    // hist atomics drained + s_wmax visible

    // coalesced uint4 flush (row base is 8KB-aligned)
    uint4* hrow4 = (uint4*)(hist + (size_t)row * NBINS);
    const uint4* sh4 = (const uint4*)s_hist;
    #pragma unroll
    for (int i = 0; i < NBINS / 4 / BLOCK; ++i)   // 2 iters
        hrow4[tid + i * BLOCK] = sh4[tid + i * BLOCK];
    if (tid == 0)
        rmaxv[row] = fmaxf(fmaxf(fmaxf(s_wmax[0], s_wmax[1]),
                                 fmaxf(s_wmax[2], s_wmax[3])), 1e-8f);
}

// ---- K2: Newton solve, ONE WAVE PER ROW, histogram in registers ----
// 2048 independent waves across 1024 SIMDs: fully parallel, no barriers,
// no LDS in the loop. Writes {beta, 1/(qmax+1e-20)} per row.
__global__ __launch_bounds__(BLOCK) void k2_newton(
        const unsigned* __restrict__ hist, const float* __restrict__ rmaxv,
        float2* __restrict__ bq, int B) {
    const int lane = threadIdx.x & 63, wid = threadIdx.x >> 6;
    const int row = blockIdx.x * 4 + wid;
    if (row >= B) return;

    // load 32 bins/lane as 8 coalesced uint4; precompute bin centers
    const uint4* h4 = (const uint4*)(hist + (size_t)row * NBINS);
    float n[BPL], m[BPL];
    #pragma unroll
    for (int k = 0; k < 8; ++k) {
        uint4 h = h4[k * 64 + lane];
        unsigned cnt[4] = {h.x, h.y, h.z, h.w};
        #pragma unroll
        for (int c = 0; c < 4; ++c) {
            const int b = k * 256 + lane * 4 + c;
            n[k * 4 + c] = (float)cnt[c];
            // arithmetic midpoint of the bin's linear range
            m[k * 4 + c] = __uint_as_float(((unsigned)(b + BIN_OFF) << 16) | 0x8000u);
        }
    }
    const float rmax = rmaxv[row];
    float eps = rmax / (logf(2.0f * (float)N_COLS) + 1e-8f);
    const float sc2 = 0.5f / (float)N_COLS;     // 2^-14 exact

    for (int it = 0; it < 20; ++it) {
        const float inv_eps = 1.0f / fmaxf(eps, 1e-8f);
        float fs = 0.0f, gs = 0.0f;             // sum n*(e-ei), sum n*(e+ei)*u
        #pragma unroll
        for (int i = 0; i < BPL; ++i) {
            float u  = m[i] * inv_eps;
            float e  = __expf(u);
            float ei = __expf(-u);
            fs = fmaf(n[i], e - ei, fs);
            gs = fmaf(n[i] * (e + ei), u, gs);
        }
        #pragma unroll
        for (int s = 32; s >= 1; s >>= 1) {
            fs += __shfl_xor(fs, s, 64);
            gs += __shfl_xor(gs, s, 64);
        }
        float val  = fmaf(fs, sc2, -1.0f);      // mean(sinh)-1
        float grad = -(gs * sc2) * inv_eps;     // mean(cosh*(-u/eps))
        float delta = val / (grad - 1e-8f);
        eps -= delta;
        if (fabsf(delta) <= 1e-5f * eps) break; // wave-uniform post-reduce
    }
    eps = fmaxf(eps, 1e-8f);
    const float beta = 1.0f / (eps + 1e-6f);
    const float um = beta * rmax;               // qmax = sinh(beta*rmax), exact rmax
    const float qmax = 0.5f * (__expf(um) - __expf(-um));
    if (lane == 0) bq[row] = make_float2(beta, 1.0f / (qmax + 1e-20f));
}

// ---- K3: epilogue streaming pass (y re-read is L3-warm from K1) ----
__global__ __launch_bounds__(BLOCK) void k3_epilogue(
        const float* __restrict__ y_pred, const float* __restrict__ y_true,
        const float* __restrict__ Lambda, const float2* __restrict__ bq,
        float* __restrict__ out, float inv_total) {
    __shared__ float s_part[4];
    const int row = blockIdx.x, tid = threadIdx.x;
    const int lane = tid & 63, wid = tid >> 6;
    const size_t base = (size_t)row * N_COLS;
    const float4* yp4  = (const float4*)(y_pred + base);
    const float4* yt4  = (const float4*)(y_true + base);
    const float4* lam4 = (const float4*)(Lambda + base);
    float* outw = out + 1 + base;   // 4B-aligned only -> scalar stores

    const float2 bqv = bq[row];     // block-uniform
    const float beta = bqv.x, inv_qmax = bqv.y;

    float s_loss = 0.0f;
    #pragma unroll
    for (int j = 0; j < F4PT; ++j) {
        const int g = j * BLOCK + tid;
        float4 a = yt4[g], b = yp4[g], L = lam4[g];
        float rr[4] = {fabsf(a.x - b.x), fabsf(a.y - b.y),
                       fabsf(a.z - b.z), fabsf(a.w - b.w)};
        float LL[4] = {L.x, L.y, L.z, L.w};
        #pragma unroll
        for (int c = 0; c < 4; ++c) {
            float u  = beta * rr[c];
            float q  = 0.5f * (__expf(u) - __expf(-u));
            float lam_it = fmaf(0.9f, q * inv_qmax, 0.1f);  // PHI, 1-PHI
            float uL = fmaf(0.99f, LL[c], 0.1f * lam_it);   // GAMMA, ETA
            outw[(size_t)g * 4 + c] = uL;
            float t = uL * rr[c];
            s_loss = fmaf(t, t, s_loss);
        }
    }
    #pragma unroll
    for (int s = 32; s >= 1; s >>= 1) s_loss += __shfl_xor(s_loss, s, 64);
    if (lane == 0) s_part[wid] = s_loss;
    __syncthreads();
    if (tid == 0) {
        float tot = (s_part[0] + s_part[1]) + (s_part[2] + s_part[3]);
        atomicAdd(out, tot * inv_total);
    }
}

extern "C" void kernel_launch(void* const* d_in, const int* in_sizes, int n_in,
                              void* d_out, int out_size, void* d_ws, size_t ws_size,
                              hipStream_t stream) {
    const float* y_pred = (const float*)d_in[0];
    const float* y_true = (const float*)d_in[1];
    const float* Lambda = (const float*)d_in[2];
    float* out = (float*)d_out;

    const int total = in_sizes[0];            // B * N
    const int B = total / N_COLS;
    const float inv_total = 1.0f / (float)total;

    // workspace layout: [hist B*NBINS u32][rmax B f32][bq B float2]
    unsigned* hist  = (unsigned*)d_ws;
    float*    rmaxv = (float*)(hist + (size_t)B * NBINS);
    float2*   bq    = (float2*)(rmaxv + B);   // 8B-aligned (B*NBINS*4 + B*4)

    hipLaunchKernelGGL(zero_out_kernel, dim3(1), dim3(64), 0, stream, out);
    hipLaunchKernelGGL(k1_hist, dim3(B), dim3(BLOCK), 0, stream,
                       y_pred, y_true, hist, rmaxv);
    hipLaunchKernelGGL(k2_newton, dim3((B + 3) / 4), dim3(BLOCK), 0, stream,
                       hist, rmaxv, bq, B);
    hipLaunchKernelGGL(k3_epilogue, dim3(B), dim3(BLOCK), 0, stream,
                       y_pred, y_true, Lambda, bq, out, inv_total);
}

// Round 4
// 228.956 us; speedup vs baseline: 1.1769x; 1.1769x over previous
//
#include <hip/hip_runtime.h>
#include <math.h>

// B=2048, N=8192, fp32. Monolithic: one block per row, one HBM pass.
#define N_COLS  8192
#define BLOCK   256
#define VPT     (N_COLS / BLOCK)   // 32 elems/thread
#define F4PT    (VPT / 4)          // 8 float4 groups/thread
#define NBINS   1024               // 16 octaves x 64 log bins over [2^-12, 2^4)
#define BIN_OFF 7360               // (127-12) << 6
#define BPL     (NBINS / 64)       // 16 bins per lane (per-wave register Newton)

// d_out[0] must be zeroed every call (harness re-poisons to 0xAA).
__global__ void zero_out_kernel(float* out) {
    if (threadIdx.x == 0 && blockIdx.x == 0) out[0] = 0.0f;
}

__global__ __launch_bounds__(BLOCK) void custom_loss_kernel(
        const float* __restrict__ y_pred,
        const float* __restrict__ y_true,
        const float* __restrict__ Lambda,
        float* __restrict__ out,      // out[0]=loss, out[1..]=updated_Lambda
        float inv_total) {
    __shared__ unsigned s_hist[NBINS];
    __shared__ float s_wmax[4];
    __shared__ float s_part[4];

    const int row  = blockIdx.x;
    const int tid  = threadIdx.x;
    const int lane = tid & 63;
    const int wid  = tid >> 6;
    const size_t base = (size_t)row * N_COLS;
    const float4* yp4  = (const float4*)(y_pred + base);
    const float4* yt4  = (const float4*)(y_true + base);
    const float4* lam4 = (const float4*)(Lambda + base);

    // zero histogram, then barrier before atomics
    #pragma unroll
    for (int i = 0; i < NBINS / BLOCK; ++i) s_hist[tid + i * BLOCK] = 0u;
    __syncthreads();

    // ---- single load phase: y -> r (regs), Lambda -> regs (prefetch) ----
    float4 r[F4PT];
    float4 L[F4PT];
    float rmax = 0.0f;
    #pragma unroll
    for (int j = 0; j < F4PT; ++j) {
        const int g = j * BLOCK + tid;     // coalesced float4
        float4 a = yt4[g], b = yp4[g];
        L[j] = lam4[g];                    // prefetch; consumed after Newton
        float4 rv;
        rv.x = fabsf(a.x - b.x); rv.y = fabsf(a.y - b.y);
        rv.z = fabsf(a.z - b.z); rv.w = fabsf(a.w - b.w);
        r[j] = rv;
        rmax = fmaxf(rmax, fmaxf(fmaxf(rv.x, rv.y), fmaxf(rv.z, rv.w)));
    }
    // log-domain histogram: bin = (float bits >> 17) - BIN_OFF, clamped
    #pragma unroll
    for (int j = 0; j < F4PT; ++j) {
        float rv[4] = {r[j].x, r[j].y, r[j].z, r[j].w};
        #pragma unroll
        for (int c = 0; c < 4; ++c) {
            int idx = (int)(__float_as_uint(rv[c]) >> 17) - BIN_OFF;
            idx = min(max(idx, 0), NBINS - 1);
            atomicAdd(&s_hist[idx], 1u);
        }
    }
    #pragma unroll
    for (int m = 32; m >= 1; m >>= 1) rmax = fmaxf(rmax, __shfl_xor(rmax, m, 64));
    if (lane == 0) s_wmax[wid] = rmax;
    __syncthreads();    // hist complete + s_wmax visible
    rmax = fmaxf(fmaxf(fmaxf(s_wmax[0], s_wmax[1]),
                       fmaxf(s_wmax[2], s_wmax[3])), 1e-8f);

    // ---- per-wave redundant Newton: hist -> regs, no barriers, no idle waves
    float n[BPL], m[BPL];
    #pragma unroll
    for (int i = 0; i < BPL; ++i) {
        const int b = lane + 64 * i;                  // conflict-free LDS read
        n[i] = (float)s_hist[b];
        // geometric-ish bin center: midpoint bit pattern of the bin's range
        m[i] = __uint_as_float(((unsigned)(b + BIN_OFF) << 17) | 0x10000u);
    }
    float eps = rmax / (logf(2.0f * (float)N_COLS) + 1e-8f);
    const float sc2 = 0.5f / (float)N_COLS;           // 2^-14 exact
    for (int it = 0; it < 20; ++it) {
        const float inv_eps = 1.0f / fmaxf(eps, 1e-8f);
        float fs = 0.0f, gs = 0.0f;                   // sum n*(e-ei), n*(e+ei)*u
        #pragma unroll
        for (int i = 0; i < BPL; ++i) {
            float u  = m[i] * inv_eps;
            float e  = __expf(u);
            float ei = __expf(-u);
            fs = fmaf(n[i], e - ei, fs);
            gs = fmaf(n[i] * (e + ei), u, gs);
        }
        #pragma unroll
        for (int s = 32; s >= 1; s >>= 1) {
            fs += __shfl_xor(fs, s, 64);
            gs += __shfl_xor(gs, s, 64);
        }
        float val  = fmaf(fs, sc2, -1.0f);            // mean(sinh)-1
        float grad = -(gs * sc2) * inv_eps;           // mean(cosh*(-u/eps))
        float delta = val / (grad - 1e-8f);
        eps -= delta;
        if (fabsf(delta) <= 1e-5f * eps) break;       // wave-uniform post-reduce
    }
    eps = fmaxf(eps, 1e-8f);
    const float beta = 1.0f / (eps + 1e-6f);
    const float um = beta * rmax;                     // qmax = sinh(beta*rmax)
    const float inv_qmax = 1.0f / (0.5f * (__expf(um) - __expf(-um)) + 1e-20f);

    // ---- epilogue: Lambda already in regs; compute, store, loss partial ----
    float* outw = out + 1 + base;   // 4B-aligned only -> scalar stores
    float s_loss = 0.0f;
    #pragma unroll
    for (int j = 0; j < F4PT; ++j) {
        const int g = j * BLOCK + tid;
        float rr[4] = {r[j].x, r[j].y, r[j].z, r[j].w};
        float LL[4] = {L[j].x, L[j].y, L[j].z, L[j].w};
        #pragma unroll
        for (int c = 0; c < 4; ++c) {
            float u  = beta * rr[c];
            float q  = 0.5f * (__expf(u) - __expf(-u));
            float lam_it = fmaf(0.9f, q * inv_qmax, 0.1f);  // PHI, 1-PHI
            float uL = fmaf(0.99f, LL[c], 0.1f * lam_it);   // GAMMA, ETA
            outw[(size_t)g * 4 + c] = uL;
            float t = uL * rr[c];
            s_loss = fmaf(t, t, s_loss);
        }
    }
    #pragma unroll
    for (int s = 32; s >= 1; s >>= 1) s_loss += __shfl_xor(s_loss, s, 64);
    __syncthreads();                 // reuse s_part safely
    if (lane == 0) s_part[wid] = s_loss;
    __syncthreads();
    if (tid == 0) {
        float tot = (s_part[0] + s_part[1]) + (s_part[2] + s_part[3]);
        atomicAdd(out, tot * inv_total);
    }
}

extern "C" void kernel_launch(void* const* d_in, const int* in_sizes, int n_in,
                              void* d_out, int out_size, void* d_ws, size_t ws_size,
                              hipStream_t stream) {
    const float* y_pred = (const float*)d_in[0];
    const float* y_true = (const float*)d_in[1];
    const float* Lambda = (const float*)d_in[2];
    float* out = (float*)d_out;

    const int total = in_sizes[0];            // B * N
    const int B = total / N_COLS;
    const float inv_total = 1.0f / (float)total;

    hipLaunchKernelGGL(zero_out_kernel, dim3(1), dim3(64), 0, stream, out);
    hipLaunchKernelGGL(custom_loss_kernel, dim3(B), dim3(BLOCK), 0, stream,
                       y_pred, y_true, Lambda, out, inv_total);
}